// Round 1
// baseline (4454.361 us; speedup 1.0000x reference)
//
#include <hip/hip_runtime.h>

// GraphSAGE 3-layer, N=50000, E=800000, D_IN=D_HID=128, D_OUT=64, fp32.
// Layer: agg[n] = sum_{e: row[e]=n} x[col[e]]*ew[e]; deg[n]=sum ew[e] (clip>=1)
//        h = [x, agg/deg]; y = h @ W^T + b; relu (layers 0,1 only)

#define D 128
#define K2 256

__global__ void deg_kernel(const int* __restrict__ row, const float* __restrict__ ew,
                           float* __restrict__ deg, int E) {
    int t = blockIdx.x * blockDim.x + threadIdx.x;
    if (t < E) atomicAdd(&deg[row[t]], ew[t]);
}

// 32 threads per edge, each thread handles 4 consecutive features (float4 gather).
__global__ void agg_kernel(const float* __restrict__ src, const int* __restrict__ row,
                           const int* __restrict__ col, const float* __restrict__ ew,
                           float* __restrict__ agg, int E) {
    long long t = (long long)blockIdx.x * blockDim.x + threadIdx.x;
    int e = (int)(t >> 5);
    if (e >= E) return;
    int lane = (int)(t & 31);
    float w = ew[e];
    int c = col[e], r = row[e];
    float4 v = *reinterpret_cast<const float4*>(src + (size_t)c * D + lane * 4);
    float* dst = agg + (size_t)r * D + lane * 4;
    atomicAdd(dst + 0, v.x * w);
    atomicAdd(dst + 1, v.y * w);
    atomicAdd(dst + 2, v.z * w);
    atomicAdd(dst + 3, v.w * w);
}

// Fused concat + linear + bias (+relu). Block: OUT threads (one per output col),
// NB=8 nodes per block. h tile staged in LDS (broadcast reads -> no bank conflicts).
template<int OUT, bool RELU>
__global__ __launch_bounds__(OUT) void sage_linear(
    const float* __restrict__ xin, const float* __restrict__ agg,
    const float* __restrict__ deg, const float* __restrict__ W,
    const float* __restrict__ bias, float* __restrict__ out, int N) {
    constexpr int NB = 8;
    __shared__ float hs[NB][K2];
    __shared__ float sinv[NB];
    int n0 = blockIdx.x * NB;
    int tid = threadIdx.x;
    if (tid < NB) {
        int n = n0 + tid;
        float dd = 1.0f;
        if (n < N) { dd = deg[n]; dd = dd > 1.0f ? dd : 1.0f; }
        sinv[tid] = 1.0f / dd;
    }
    __syncthreads();
    constexpr int V4 = NB * (K2 / 4);   // 512 float4 slots
    for (int i = tid; i < V4; i += OUT) {
        int j = i >> 6;                 // node within tile
        int pos = i & 63;               // float4 index within row of 256
        int n = n0 + j;
        float4 v = make_float4(0.f, 0.f, 0.f, 0.f);
        if (n < N) {
            if (pos < 32) {
                v = *reinterpret_cast<const float4*>(xin + (size_t)n * D + pos * 4);
            } else {
                v = *reinterpret_cast<const float4*>(agg + (size_t)n * D + (pos - 32) * 4);
                float s = sinv[j];
                v.x *= s; v.y *= s; v.z *= s; v.w *= s;
            }
        }
        *reinterpret_cast<float4*>(&hs[j][pos * 4]) = v;
    }
    __syncthreads();
    float acc[NB];
#pragma unroll
    for (int j = 0; j < NB; j++) acc[j] = 0.f;
    const float* wrow = W + (size_t)tid * K2;
    for (int k4 = 0; k4 < K2 / 4; ++k4) {
        float4 w4 = *reinterpret_cast<const float4*>(wrow + k4 * 4);
#pragma unroll
        for (int j = 0; j < NB; j++) {
            float4 h4 = *reinterpret_cast<const float4*>(&hs[j][k4 * 4]);
            acc[j] += w4.x * h4.x + w4.y * h4.y + w4.z * h4.z + w4.w * h4.w;
        }
    }
    float bb = bias[tid];
#pragma unroll
    for (int j = 0; j < NB; j++) {
        int n = n0 + j;
        if (n < N) {
            float y = acc[j] + bb;
            if (RELU) y = y > 0.f ? y : 0.f;
            out[(size_t)n * OUT + tid] = y;
        }
    }
}

extern "C" void kernel_launch(void* const* d_in, const int* in_sizes, int n_in,
                              void* d_out, int out_size, void* d_ws, size_t ws_size,
                              hipStream_t stream) {
    const float* x  = (const float*)d_in[0];
    const int*   ei = (const int*)d_in[1];
    const float* ew = (const float*)d_in[2];
    const float* W0 = (const float*)d_in[3];
    const float* b0 = (const float*)d_in[4];
    const float* W1 = (const float*)d_in[5];
    const float* b1 = (const float*)d_in[6];
    const float* W2 = (const float*)d_in[7];
    const float* b2 = (const float*)d_in[8];
    float* out = (float*)d_out;

    const int N = 50000;
    const int E = in_sizes[2];          // 800000
    const int* row = ei;
    const int* col = ei + E;

    // workspace layout (floats): agg[N*128] | deg[N pad] | h0[N*128] | h1[N*128]
    float* ws  = (float*)d_ws;
    float* agg = ws;
    float* deg = agg + (size_t)N * D;
    size_t degPad = (size_t)((N + 63) & ~63);
    float* h0  = deg + degPad;
    float* h1  = h0 + (size_t)N * D;

    // degree (layer-invariant)
    hipMemsetAsync(deg, 0, (size_t)N * sizeof(float), stream);
    deg_kernel<<<(E + 255) / 256, 256, 0, stream>>>(row, ew, deg, E);

    long long aggT = (long long)E * 32;
    int aggBlocks = (int)((aggT + 255) / 256);
    int linBlocks = (N + 7) / 8;

    // layer 0
    hipMemsetAsync(agg, 0, (size_t)N * D * sizeof(float), stream);
    agg_kernel<<<aggBlocks, 256, 0, stream>>>(x, row, col, ew, agg, E);
    sage_linear<128, true><<<linBlocks, 128, 0, stream>>>(x, agg, deg, W0, b0, h0, N);

    // layer 1
    hipMemsetAsync(agg, 0, (size_t)N * D * sizeof(float), stream);
    agg_kernel<<<aggBlocks, 256, 0, stream>>>(h0, row, col, ew, agg, E);
    sage_linear<128, true><<<linBlocks, 128, 0, stream>>>(h0, agg, deg, W1, b1, h1, N);

    // layer 2 (OUT=64, no relu)
    hipMemsetAsync(agg, 0, (size_t)N * D * sizeof(float), stream);
    agg_kernel<<<aggBlocks, 256, 0, stream>>>(h1, row, col, ew, agg, E);
    sage_linear<64, false><<<linBlocks, 64, 0, stream>>>(h1, agg, deg, W2, b2, out, N);
}

// Round 2
// 650.605 us; speedup vs baseline: 6.8465x; 6.8465x over previous
//
#include <hip/hip_runtime.h>

// GraphSAGE 3-layer, N=50000, E=800000, D=128, D_OUT=64, fp32.
// R2: atomic scatter -> device-built CSR + gather aggregation (no float atomics).

#define D 128
#define K2 256

// ---------- CSR build ----------
__global__ void hist_kernel(const int* __restrict__ row, int* __restrict__ cnt, int E) {
    int e = blockIdx.x * blockDim.x + threadIdx.x;
    if (e < E) atomicAdd(&cnt[row[e]], 1);
}

// exclusive scan, 256-wide blocks; excl -> rowptr[0..N), block sums -> bsum
__global__ void scan1_kernel(const int* __restrict__ cnt, int* __restrict__ rowptr,
                             int* __restrict__ bsum, int N) {
    __shared__ int s[256];
    int tid = threadIdx.x;
    int gid = blockIdx.x * 256 + tid;
    int v = (gid < N) ? cnt[gid] : 0;
    s[tid] = v;
    __syncthreads();
    for (int off = 1; off < 256; off <<= 1) {
        int t = (tid >= off) ? s[tid - off] : 0;
        __syncthreads();
        s[tid] += t;
        __syncthreads();
    }
    if (gid < N) rowptr[gid] = s[tid] - v;   // exclusive within block
    if (tid == 255) bsum[blockIdx.x] = s[255];
}

__global__ void scan2_kernel(int* __restrict__ bsum, int* __restrict__ boff, int nb) {
    __shared__ int s[256];
    int tid = threadIdx.x;
    int v = (tid < nb) ? bsum[tid] : 0;
    s[tid] = v;
    __syncthreads();
    for (int off = 1; off < 256; off <<= 1) {
        int t = (tid >= off) ? s[tid - off] : 0;
        __syncthreads();
        s[tid] += t;
        __syncthreads();
    }
    if (tid < nb) boff[tid] = s[tid] - v;    // exclusive
}

__global__ void scan3_kernel(int* __restrict__ rowptr, const int* __restrict__ boff,
                             int* __restrict__ cursor, int N, int E) {
    int gid = blockIdx.x * 256 + threadIdx.x;
    if (gid < N) {
        int v = rowptr[gid] + boff[gid >> 8];
        rowptr[gid] = v;
        cursor[gid] = v;
    } else if (gid == N) {
        rowptr[N] = E;
    }
}

__global__ void scatter_kernel(const int* __restrict__ row, const int* __restrict__ col,
                               const float* __restrict__ ew, int* __restrict__ cursor,
                               int* __restrict__ ecol, float* __restrict__ eww, int E) {
    int e = blockIdx.x * blockDim.x + threadIdx.x;
    if (e >= E) return;
    int p = atomicAdd(&cursor[row[e]], 1);
    ecol[p] = col[e];
    eww[p] = ew[e];
}

// ---------- gather aggregation: 32 lanes per node, float4 per lane ----------
// writes agg already divided by clipped degree
__global__ void gather_agg(const float* __restrict__ src, const int* __restrict__ rowptr,
                           const int* __restrict__ ecol, const float* __restrict__ eww,
                           float* __restrict__ agg, int N) {
    int t = blockIdx.x * blockDim.x + threadIdx.x;
    int n = t >> 5;
    if (n >= N) return;
    int lane = t & 31;
    int beg = rowptr[n], end = rowptr[n + 1];
    float4 acc = make_float4(0.f, 0.f, 0.f, 0.f);
    float ds = 0.f;
    for (int e = beg; e < end; ++e) {
        int c = ecol[e];
        float w = eww[e];
        float4 v = *reinterpret_cast<const float4*>(src + (size_t)c * D + lane * 4);
        acc.x += v.x * w; acc.y += v.y * w; acc.z += v.z * w; acc.w += v.w * w;
        ds += w;
    }
    float inv = 1.0f / (ds > 1.f ? ds : 1.f);
    float4 o = make_float4(acc.x * inv, acc.y * inv, acc.z * inv, acc.w * inv);
    *reinterpret_cast<float4*>(agg + (size_t)n * D + lane * 4) = o;
}

// ---------- fused concat + linear + bias (+relu); agg arrives pre-scaled ----------
template<int OUT, bool RELU>
__global__ __launch_bounds__(OUT) void sage_linear(
    const float* __restrict__ xin, const float* __restrict__ agg,
    const float* __restrict__ W, const float* __restrict__ bias,
    float* __restrict__ out, int N) {
    constexpr int NB = 8;
    __shared__ float hs[NB][K2];
    int n0 = blockIdx.x * NB;
    int tid = threadIdx.x;
    constexpr int V4 = NB * (K2 / 4);   // 512 float4 slots
    for (int i = tid; i < V4; i += OUT) {
        int j = i >> 6;
        int pos = i & 63;
        int n = n0 + j;
        float4 v = make_float4(0.f, 0.f, 0.f, 0.f);
        if (n < N) {
            if (pos < 32) v = *reinterpret_cast<const float4*>(xin + (size_t)n * D + pos * 4);
            else          v = *reinterpret_cast<const float4*>(agg + (size_t)n * D + (pos - 32) * 4);
        }
        *reinterpret_cast<float4*>(&hs[j][pos * 4]) = v;
    }
    __syncthreads();
    float acc[NB];
#pragma unroll
    for (int j = 0; j < NB; j++) acc[j] = 0.f;
    const float* wrow = W + (size_t)tid * K2;
    for (int k4 = 0; k4 < K2 / 4; ++k4) {
        float4 w4 = *reinterpret_cast<const float4*>(wrow + k4 * 4);
#pragma unroll
        for (int j = 0; j < NB; j++) {
            float4 h4 = *reinterpret_cast<const float4*>(&hs[j][k4 * 4]);
            acc[j] += w4.x * h4.x + w4.y * h4.y + w4.z * h4.z + w4.w * h4.w;
        }
    }
    float bb = bias[tid];
#pragma unroll
    for (int j = 0; j < NB; j++) {
        int n = n0 + j;
        if (n < N) {
            float y = acc[j] + bb;
            if (RELU) y = y > 0.f ? y : 0.f;
            out[(size_t)n * OUT + tid] = y;
        }
    }
}

extern "C" void kernel_launch(void* const* d_in, const int* in_sizes, int n_in,
                              void* d_out, int out_size, void* d_ws, size_t ws_size,
                              hipStream_t stream) {
    const float* x  = (const float*)d_in[0];
    const int*   ei = (const int*)d_in[1];
    const float* ew = (const float*)d_in[2];
    const float* W0 = (const float*)d_in[3];
    const float* b0 = (const float*)d_in[4];
    const float* W1 = (const float*)d_in[5];
    const float* b1 = (const float*)d_in[6];
    const float* W2 = (const float*)d_in[7];
    const float* b2 = (const float*)d_in[8];
    float* out = (float*)d_out;

    const int N = 50000;
    const int E = in_sizes[2];          // 800000
    const int* row = ei;
    const int* col = ei + E;

    // float regions (each N*D = 6.4M floats):
    //   bufA: agg(L0) then h1        bufB: h0 then agg(L2)        bufC: agg(L1)
    // CSR: rowptr[N+1], ecol[E], eww[E] after the float regions.
    // CSR-build scratch (cnt, cursor, bsum, boff) aliases bufC (written only at L1).
    float* ws   = (float*)d_ws;
    size_t ND   = (size_t)N * D;
    float* bufA = ws;
    float* bufB = bufA + ND;
    float* bufC = bufB + ND;
    int*   rowptr = (int*)(bufC + ND);
    int*   ecol   = rowptr + (N + 1);
    float* eww    = (float*)(ecol + E);

    int* cnt    = (int*)bufC;           // N ints
    int* cursor = cnt + N;              // N ints
    int* bsum   = cursor + N;           // <=256 ints
    int* boff   = bsum + 256;           // <=256 ints

    int nbScan = (N + 255) / 256;       // 196

    // ---- CSR build ----
    hipMemsetAsync(cnt, 0, (size_t)N * sizeof(int), stream);
    hist_kernel<<<(E + 255) / 256, 256, 0, stream>>>(row, cnt, E);
    scan1_kernel<<<nbScan, 256, 0, stream>>>(cnt, rowptr, bsum, N);
    scan2_kernel<<<1, 256, 0, stream>>>(bsum, boff, nbScan);
    scan3_kernel<<<(N + 256) / 256 + 1, 256, 0, stream>>>(rowptr, boff, cursor, N, E);
    scatter_kernel<<<(E + 255) / 256, 256, 0, stream>>>(row, col, ew, cursor, ecol, eww, E);

    int aggBlocks = (N * 32 + 255) / 256;
    int linBlocks = (N + 7) / 8;

    // layer 0: agg(x)->bufA ; linear(x,bufA)->bufB(h0)
    gather_agg<<<aggBlocks, 256, 0, stream>>>(x, rowptr, ecol, eww, bufA, N);
    sage_linear<128, true><<<linBlocks, 128, 0, stream>>>(x, bufA, W0, b0, bufB, N);

    // layer 1: agg(h0)->bufC ; linear(h0,bufC)->bufA(h1)
    gather_agg<<<aggBlocks, 256, 0, stream>>>(bufB, rowptr, ecol, eww, bufC, N);
    sage_linear<128, true><<<linBlocks, 128, 0, stream>>>(bufB, bufC, W1, b1, bufA, N);

    // layer 2: agg(h1)->bufB ; linear(h1,bufB)->out  (OUT=64, no relu)
    gather_agg<<<aggBlocks, 256, 0, stream>>>(bufA, rowptr, ecol, eww, bufB, N);
    sage_linear<64, false><<<linBlocks, 64, 0, stream>>>(bufA, bufB, W2, b2, out, N);
}

// Round 3
// 566.581 us; speedup vs baseline: 7.8618x; 1.1483x over previous
//
#include <hip/hip_runtime.h>

// GraphSAGE 3-layer, N=50000, E=800000, D=128, D_OUT=64, fp32.
// R3: register-tiled fp32 GEMM (64-node x OUT tile, 4x8 per thread) +
//     full-wave gather (2 edge slots x 32 feature lanes, unroll 2).

#define D 128
#define K2 256

// ---------- CSR build ----------
__global__ void hist_kernel(const int* __restrict__ row, int* __restrict__ cnt, int E) {
    int e = blockIdx.x * blockDim.x + threadIdx.x;
    if (e < E) atomicAdd(&cnt[row[e]], 1);
}

__global__ void scan1_kernel(const int* __restrict__ cnt, int* __restrict__ rowptr,
                             int* __restrict__ bsum, int N) {
    __shared__ int s[256];
    int tid = threadIdx.x;
    int gid = blockIdx.x * 256 + tid;
    int v = (gid < N) ? cnt[gid] : 0;
    s[tid] = v;
    __syncthreads();
    for (int off = 1; off < 256; off <<= 1) {
        int t = (tid >= off) ? s[tid - off] : 0;
        __syncthreads();
        s[tid] += t;
        __syncthreads();
    }
    if (gid < N) rowptr[gid] = s[tid] - v;
    if (tid == 255) bsum[blockIdx.x] = s[255];
}

__global__ void scan2_kernel(int* __restrict__ bsum, int* __restrict__ boff, int nb) {
    __shared__ int s[256];
    int tid = threadIdx.x;
    int v = (tid < nb) ? bsum[tid] : 0;
    s[tid] = v;
    __syncthreads();
    for (int off = 1; off < 256; off <<= 1) {
        int t = (tid >= off) ? s[tid - off] : 0;
        __syncthreads();
        s[tid] += t;
        __syncthreads();
    }
    if (tid < nb) boff[tid] = s[tid] - v;
}

__global__ void scan3_kernel(int* __restrict__ rowptr, const int* __restrict__ boff,
                             int* __restrict__ cursor, int N, int E) {
    int gid = blockIdx.x * 256 + threadIdx.x;
    if (gid < N) {
        int v = rowptr[gid] + boff[gid >> 8];
        rowptr[gid] = v;
        cursor[gid] = v;
    } else if (gid == N) {
        rowptr[N] = E;
    }
}

__global__ void scatter_kernel(const int* __restrict__ row, const int* __restrict__ col,
                               const float* __restrict__ ew, int* __restrict__ cursor,
                               int* __restrict__ ecol, float* __restrict__ eww, int E) {
    int e = blockIdx.x * blockDim.x + threadIdx.x;
    if (e >= E) return;
    int p = atomicAdd(&cursor[row[e]], 1);
    ecol[p] = col[e];
    eww[p] = ew[e];
}

// ---------- gather aggregation ----------
// One wave per node: 2 edge slots x 32 feature lanes (float4/lane), unroll x2.
// Writes agg pre-divided by clipped degree.
__global__ void gather_agg(const float* __restrict__ src, const int* __restrict__ rowptr,
                           const int* __restrict__ ecol, const float* __restrict__ eww,
                           float* __restrict__ agg, int N) {
    int wid = (int)((blockIdx.x * (long long)blockDim.x + threadIdx.x) >> 6);
    if (wid >= N) return;
    int lane = threadIdx.x & 63;
    int esub = lane >> 5;            // edge slot 0/1
    int fl = lane & 31;              // float4 index within the 128-float row
    int beg = rowptr[wid], end = rowptr[wid + 1];
    float4 acc = make_float4(0.f, 0.f, 0.f, 0.f);
    float ds = 0.f;
    int e = beg + esub;
    for (; e + 2 < end; e += 4) {    // two edges in flight per slot
        int c0 = ecol[e],     c1 = ecol[e + 2];
        float w0 = eww[e],    w1 = eww[e + 2];
        float4 v0 = *reinterpret_cast<const float4*>(src + (size_t)c0 * D + fl * 4);
        float4 v1 = *reinterpret_cast<const float4*>(src + (size_t)c1 * D + fl * 4);
        acc.x += v0.x * w0 + v1.x * w1;
        acc.y += v0.y * w0 + v1.y * w1;
        acc.z += v0.z * w0 + v1.z * w1;
        acc.w += v0.w * w0 + v1.w * w1;
        ds += w0 + w1;
    }
    for (; e < end; e += 2) {
        int c = ecol[e];
        float w = eww[e];
        float4 v = *reinterpret_cast<const float4*>(src + (size_t)c * D + fl * 4);
        acc.x += v.x * w; acc.y += v.y * w; acc.z += v.z * w; acc.w += v.w * w;
        ds += w;
    }
    // combine the two edge slots (lane ^ 32)
    acc.x += __shfl_xor(acc.x, 32);
    acc.y += __shfl_xor(acc.y, 32);
    acc.z += __shfl_xor(acc.z, 32);
    acc.w += __shfl_xor(acc.w, 32);
    ds    += __shfl_xor(ds, 32);
    float inv = 1.0f / (ds > 1.f ? ds : 1.f);
    if (esub == 0) {
        float4 o = make_float4(acc.x * inv, acc.y * inv, acc.z * inv, acc.w * inv);
        *reinterpret_cast<float4*>(agg + (size_t)wid * D + fl * 4) = o;
    }
}

// ---------- tiled GEMM: C[N,OUT] = [x|agg] @ W^T + b ----------
// Block 256 threads (tx=tid&15, ty=tid>>4). Tile: 64 nodes x OUT cols.
// Thread computes nodes {ty+16i} x cols {tx+16j}. K staged in 4 chunks of 64.
template<int OUT, bool RELU>
__global__ __launch_bounds__(256) void sage_linear(
    const float* __restrict__ xin, const float* __restrict__ agg,
    const float* __restrict__ W, const float* __restrict__ bias,
    float* __restrict__ out, int N) {
    constexpr int JC = OUT / 16;          // cols per thread (8 or 4)
    __shared__ float hs[64][65];
    __shared__ float ws[OUT][65];
    int tid = threadIdx.x;
    int tx = tid & 15, ty = tid >> 4;
    int n0 = blockIdx.x * 64;
    float acc[4][JC];
#pragma unroll
    for (int i = 0; i < 4; i++)
#pragma unroll
        for (int j = 0; j < JC; j++) acc[i][j] = 0.f;

    for (int kc = 0; kc < K2; kc += 64) {
        const float* src = (kc < D) ? xin : agg;
        int cb = kc & (D - 1);
        // stage H chunk: 64 rows x 16 float4
        for (int s = tid; s < 64 * 16; s += 256) {
            int r = s >> 4, f4 = s & 15;
            int n = n0 + r;
            float4 v = make_float4(0.f, 0.f, 0.f, 0.f);
            if (n < N) v = *reinterpret_cast<const float4*>(src + (size_t)n * D + cb + f4 * 4);
            *reinterpret_cast<float4*>(&hs[r][f4 * 4]) = v;
        }
        // stage W chunk: OUT rows x 16 float4
        for (int s = tid; s < OUT * 16; s += 256) {
            int r = s >> 4, f4 = s & 15;
            *reinterpret_cast<float4*>(&ws[r][f4 * 4]) =
                *reinterpret_cast<const float4*>(W + (size_t)r * K2 + kc + f4 * 4);
        }
        __syncthreads();
        for (int k4 = 0; k4 < 16; ++k4) {
            float4 h4[4];
#pragma unroll
            for (int i = 0; i < 4; i++) h4[i] = *reinterpret_cast<float4*>(&hs[ty + 16 * i][k4 * 4]);
#pragma unroll
            for (int j = 0; j < JC; j++) {
                float4 w4 = *reinterpret_cast<float4*>(&ws[tx + 16 * j][k4 * 4]);
#pragma unroll
                for (int i = 0; i < 4; i++)
                    acc[i][j] += h4[i].x * w4.x + h4[i].y * w4.y + h4[i].z * w4.z + h4[i].w * w4.w;
            }
        }
        __syncthreads();
    }
#pragma unroll
    for (int j = 0; j < JC; j++) {
        int colj = tx + 16 * j;
        float bb = bias[colj];
#pragma unroll
        for (int i = 0; i < 4; i++) {
            int n = n0 + ty + 16 * i;
            if (n < N) {
                float y = acc[i][j] + bb;
                if (RELU) y = y > 0.f ? y : 0.f;
                out[(size_t)n * OUT + colj] = y;
            }
        }
    }
}

extern "C" void kernel_launch(void* const* d_in, const int* in_sizes, int n_in,
                              void* d_out, int out_size, void* d_ws, size_t ws_size,
                              hipStream_t stream) {
    const float* x  = (const float*)d_in[0];
    const int*   ei = (const int*)d_in[1];
    const float* ew = (const float*)d_in[2];
    const float* W0 = (const float*)d_in[3];
    const float* b0 = (const float*)d_in[4];
    const float* W1 = (const float*)d_in[5];
    const float* b1 = (const float*)d_in[6];
    const float* W2 = (const float*)d_in[7];
    const float* b2 = (const float*)d_in[8];
    float* out = (float*)d_out;

    const int N = 50000;
    const int E = in_sizes[2];          // 800000
    const int* row = ei;
    const int* col = ei + E;

    // float regions (each N*D = 6.4M floats):
    //   bufA: agg(L0) then h1        bufB: h0 then agg(L2)        bufC: agg(L1)
    // CSR: rowptr[N+1], ecol[E], eww[E] after the float regions.
    // CSR-build scratch aliases bufC (only written at L1, after scatter done).
    float* ws   = (float*)d_ws;
    size_t ND   = (size_t)N * D;
    float* bufA = ws;
    float* bufB = bufA + ND;
    float* bufC = bufB + ND;
    int*   rowptr = (int*)(bufC + ND);
    int*   ecol   = rowptr + (N + 1);
    float* eww    = (float*)(ecol + E);

    int* cnt    = (int*)bufC;
    int* cursor = cnt + N;
    int* bsum   = cursor + N;
    int* boff   = bsum + 256;

    int nbScan = (N + 255) / 256;       // 196

    // ---- CSR build ----
    hipMemsetAsync(cnt, 0, (size_t)N * sizeof(int), stream);
    hist_kernel<<<(E + 255) / 256, 256, 0, stream>>>(row, cnt, E);
    scan1_kernel<<<nbScan, 256, 0, stream>>>(cnt, rowptr, bsum, N);
    scan2_kernel<<<1, 256, 0, stream>>>(bsum, boff, nbScan);
    scan3_kernel<<<(N + 256) / 256 + 1, 256, 0, stream>>>(rowptr, boff, cursor, N, E);
    scatter_kernel<<<(E + 255) / 256, 256, 0, stream>>>(row, col, ew, cursor, ecol, eww, E);

    int aggBlocks = (int)(((long long)N * 64 + 255) / 256);
    int linBlocks = (N + 63) / 64;

    // layer 0: agg(x)->bufA ; linear(x,bufA)->bufB(h0)
    gather_agg<<<aggBlocks, 256, 0, stream>>>(x, rowptr, ecol, eww, bufA, N);
    sage_linear<128, true><<<linBlocks, 256, 0, stream>>>(x, bufA, W0, b0, bufB, N);

    // layer 1: agg(h0)->bufC ; linear(h0,bufC)->bufA(h1)
    gather_agg<<<aggBlocks, 256, 0, stream>>>(bufB, rowptr, ecol, eww, bufC, N);
    sage_linear<128, true><<<linBlocks, 256, 0, stream>>>(bufB, bufC, W1, b1, bufA, N);

    // layer 2: agg(h1)->bufB ; linear(h1,bufB)->out  (OUT=64, no relu)
    gather_agg<<<aggBlocks, 256, 0, stream>>>(bufA, rowptr, ecol, eww, bufB, N);
    sage_linear<64, false><<<linBlocks, 256, 0, stream>>>(bufA, bufB, W2, b2, out, N);
}

// Round 4
// 530.721 us; speedup vs baseline: 8.3930x; 1.0676x over previous
//
#include <hip/hip_runtime.h>

// GraphSAGE 3-layer, N=50000, E=800000, D=128, D_OUT=64, fp32.
// R4: GEMM LDS pad 65->68 (kills 4-way bank conflicts: stride = 4 mod 32),
//     gather unroll x4 with packed int2 edges (8 rows in flight/wave),
//     CSR scatter writes one int2 per edge.

#define D 128
#define K2 256

// ---------- CSR build ----------
__global__ void hist_kernel(const int* __restrict__ row, int* __restrict__ cnt, int E) {
    int e = blockIdx.x * blockDim.x + threadIdx.x;
    if (e < E) atomicAdd(&cnt[row[e]], 1);
}

__global__ void scan1_kernel(const int* __restrict__ cnt, int* __restrict__ rowptr,
                             int* __restrict__ bsum, int N) {
    __shared__ int s[256];
    int tid = threadIdx.x;
    int gid = blockIdx.x * 256 + tid;
    int v = (gid < N) ? cnt[gid] : 0;
    s[tid] = v;
    __syncthreads();
    for (int off = 1; off < 256; off <<= 1) {
        int t = (tid >= off) ? s[tid - off] : 0;
        __syncthreads();
        s[tid] += t;
        __syncthreads();
    }
    if (gid < N) rowptr[gid] = s[tid] - v;
    if (tid == 255) bsum[blockIdx.x] = s[255];
}

__global__ void scan2_kernel(int* __restrict__ bsum, int* __restrict__ boff, int nb) {
    __shared__ int s[256];
    int tid = threadIdx.x;
    int v = (tid < nb) ? bsum[tid] : 0;
    s[tid] = v;
    __syncthreads();
    for (int off = 1; off < 256; off <<= 1) {
        int t = (tid >= off) ? s[tid - off] : 0;
        __syncthreads();
        s[tid] += t;
        __syncthreads();
    }
    if (tid < nb) boff[tid] = s[tid] - v;
}

__global__ void scan3_kernel(int* __restrict__ rowptr, const int* __restrict__ boff,
                             int* __restrict__ cursor, int N, int E) {
    int gid = blockIdx.x * 256 + threadIdx.x;
    if (gid < N) {
        int v = rowptr[gid] + boff[gid >> 8];
        rowptr[gid] = v;
        cursor[gid] = v;
    } else if (gid == N) {
        rowptr[N] = E;
    }
}

__global__ void scatter_kernel(const int* __restrict__ row, const int* __restrict__ col,
                               const float* __restrict__ ew, int* __restrict__ cursor,
                               int2* __restrict__ ep, int E) {
    int e = blockIdx.x * blockDim.x + threadIdx.x;
    if (e >= E) return;
    int p = atomicAdd(&cursor[row[e]], 1);
    ep[p] = make_int2(col[e], __float_as_int(ew[e]));
}

// ---------- gather aggregation ----------
// One wave per node: 2 edge slots x 32 feature lanes (float4/lane), unroll x4
// (4 feature rows in flight per slot = 8 per wave). Packed (col,w) int2 edges.
// Writes agg pre-divided by clipped degree.
__global__ void gather_agg(const float* __restrict__ src, const int* __restrict__ rowptr,
                           const int2* __restrict__ ep, float* __restrict__ agg, int N) {
    int wid = (int)((blockIdx.x * (long long)blockDim.x + threadIdx.x) >> 6);
    if (wid >= N) return;
    int lane = threadIdx.x & 63;
    int esub = lane >> 5;            // edge slot 0/1
    int fl = lane & 31;              // float4 index within the 128-float row
    int beg = rowptr[wid], end = rowptr[wid + 1];
    float4 acc = make_float4(0.f, 0.f, 0.f, 0.f);
    float ds = 0.f;
    int e = beg + esub;
    for (; e + 6 < end; e += 8) {    // 4 edges in flight per slot
        int2 p0 = ep[e];
        int2 p1 = ep[e + 2];
        int2 p2 = ep[e + 4];
        int2 p3 = ep[e + 6];
        float w0 = __int_as_float(p0.y), w1 = __int_as_float(p1.y);
        float w2 = __int_as_float(p2.y), w3 = __int_as_float(p3.y);
        float4 v0 = *reinterpret_cast<const float4*>(src + (size_t)p0.x * D + fl * 4);
        float4 v1 = *reinterpret_cast<const float4*>(src + (size_t)p1.x * D + fl * 4);
        float4 v2 = *reinterpret_cast<const float4*>(src + (size_t)p2.x * D + fl * 4);
        float4 v3 = *reinterpret_cast<const float4*>(src + (size_t)p3.x * D + fl * 4);
        acc.x += v0.x * w0 + v1.x * w1 + v2.x * w2 + v3.x * w3;
        acc.y += v0.y * w0 + v1.y * w1 + v2.y * w2 + v3.y * w3;
        acc.z += v0.z * w0 + v1.z * w1 + v2.z * w2 + v3.z * w3;
        acc.w += v0.w * w0 + v1.w * w1 + v2.w * w2 + v3.w * w3;
        ds += w0 + w1 + w2 + w3;
    }
    for (; e < end; e += 2) {
        int2 p = ep[e];
        float w = __int_as_float(p.y);
        float4 v = *reinterpret_cast<const float4*>(src + (size_t)p.x * D + fl * 4);
        acc.x += v.x * w; acc.y += v.y * w; acc.z += v.z * w; acc.w += v.w * w;
        ds += w;
    }
    // combine the two edge slots (lane ^ 32)
    acc.x += __shfl_xor(acc.x, 32);
    acc.y += __shfl_xor(acc.y, 32);
    acc.z += __shfl_xor(acc.z, 32);
    acc.w += __shfl_xor(acc.w, 32);
    ds    += __shfl_xor(ds, 32);
    float inv = 1.0f / (ds > 1.f ? ds : 1.f);
    if (esub == 0) {
        float4 o = make_float4(acc.x * inv, acc.y * inv, acc.z * inv, acc.w * inv);
        *reinterpret_cast<float4*>(agg + (size_t)wid * D + fl * 4) = o;
    }
}

// ---------- tiled GEMM: C[N,OUT] = [x|agg] @ W^T + b ----------
// Block 256 threads (tx=tid&15, ty=tid>>4). Tile: 64 nodes x OUT cols.
// Thread computes nodes {ty+16i} x cols {tx+16j}. K staged in 4 chunks of 64.
// LDS pad 68: stride = 4 mod 32 banks -> h-reads 16 disjoint banks (broadcast),
// w-reads 2-way (free per m136).
template<int OUT, bool RELU>
__global__ __launch_bounds__(256) void sage_linear(
    const float* __restrict__ xin, const float* __restrict__ agg,
    const float* __restrict__ W, const float* __restrict__ bias,
    float* __restrict__ out, int N) {
    constexpr int JC = OUT / 16;          // cols per thread (8 or 4)
    __shared__ float hs[64][68];
    __shared__ float ws[OUT][68];
    int tid = threadIdx.x;
    int tx = tid & 15, ty = tid >> 4;
    int n0 = blockIdx.x * 64;
    float acc[4][JC];
#pragma unroll
    for (int i = 0; i < 4; i++)
#pragma unroll
        for (int j = 0; j < JC; j++) acc[i][j] = 0.f;

    for (int kc = 0; kc < K2; kc += 64) {
        const float* src = (kc < D) ? xin : agg;
        int cb = kc & (D - 1);
        // stage H chunk: 64 rows x 16 float4
        for (int s = tid; s < 64 * 16; s += 256) {
            int r = s >> 4, f4 = s & 15;
            int n = n0 + r;
            float4 v = make_float4(0.f, 0.f, 0.f, 0.f);
            if (n < N) v = *reinterpret_cast<const float4*>(src + (size_t)n * D + cb + f4 * 4);
            *reinterpret_cast<float4*>(&hs[r][f4 * 4]) = v;
        }
        // stage W chunk: OUT rows x 16 float4
        for (int s = tid; s < OUT * 16; s += 256) {
            int r = s >> 4, f4 = s & 15;
            *reinterpret_cast<float4*>(&ws[r][f4 * 4]) =
                *reinterpret_cast<const float4*>(W + (size_t)r * K2 + kc + f4 * 4);
        }
        __syncthreads();
        for (int k4 = 0; k4 < 16; ++k4) {
            float4 h4[4];
#pragma unroll
            for (int i = 0; i < 4; i++) h4[i] = *reinterpret_cast<float4*>(&hs[ty + 16 * i][k4 * 4]);
#pragma unroll
            for (int j = 0; j < JC; j++) {
                float4 w4 = *reinterpret_cast<float4*>(&ws[tx + 16 * j][k4 * 4]);
#pragma unroll
                for (int i = 0; i < 4; i++)
                    acc[i][j] += h4[i].x * w4.x + h4[i].y * w4.y + h4[i].z * w4.z + h4[i].w * w4.w;
            }
        }
        __syncthreads();
    }
#pragma unroll
    for (int j = 0; j < JC; j++) {
        int colj = tx + 16 * j;
        float bb = bias[colj];
#pragma unroll
        for (int i = 0; i < 4; i++) {
            int n = n0 + ty + 16 * i;
            if (n < N) {
                float y = acc[i][j] + bb;
                if (RELU) y = y > 0.f ? y : 0.f;
                out[(size_t)n * OUT + colj] = y;
            }
        }
    }
}

extern "C" void kernel_launch(void* const* d_in, const int* in_sizes, int n_in,
                              void* d_out, int out_size, void* d_ws, size_t ws_size,
                              hipStream_t stream) {
    const float* x  = (const float*)d_in[0];
    const int*   ei = (const int*)d_in[1];
    const float* ew = (const float*)d_in[2];
    const float* W0 = (const float*)d_in[3];
    const float* b0 = (const float*)d_in[4];
    const float* W1 = (const float*)d_in[5];
    const float* b1 = (const float*)d_in[6];
    const float* W2 = (const float*)d_in[7];
    const float* b2 = (const float*)d_in[8];
    float* out = (float*)d_out;

    const int N = 50000;
    const int E = in_sizes[2];          // 800000
    const int* row = ei;
    const int* col = ei + E;

    // float regions (each N*D = 6.4M floats):
    //   bufA: agg(L0) then h1        bufB: h0 then agg(L2)        bufC: agg(L1)
    // CSR: epack[E] (int2), rowptr[N+1] after the float regions.
    // CSR-build scratch aliases bufC (only written at L1, after build done).
    float* ws   = (float*)d_ws;
    size_t ND   = (size_t)N * D;
    float* bufA = ws;
    float* bufB = bufA + ND;
    float* bufC = bufB + ND;
    int2*  ep     = (int2*)(bufC + ND);
    int*   rowptr = (int*)(ep + E);

    int* cnt    = (int*)bufC;
    int* cursor = cnt + N;
    int* bsum   = cursor + N;
    int* boff   = bsum + 256;

    int nbScan = (N + 255) / 256;       // 196

    // ---- CSR build ----
    hipMemsetAsync(cnt, 0, (size_t)N * sizeof(int), stream);
    hist_kernel<<<(E + 255) / 256, 256, 0, stream>>>(row, cnt, E);
    scan1_kernel<<<nbScan, 256, 0, stream>>>(cnt, rowptr, bsum, N);
    scan2_kernel<<<1, 256, 0, stream>>>(bsum, boff, nbScan);
    scan3_kernel<<<(N + 256) / 256 + 1, 256, 0, stream>>>(rowptr, boff, cursor, N, E);
    scatter_kernel<<<(E + 255) / 256, 256, 0, stream>>>(row, col, ew, cursor, ep, E);

    int aggBlocks = (int)(((long long)N * 64 + 255) / 256);
    int linBlocks = (N + 63) / 64;

    // layer 0: agg(x)->bufA ; linear(x,bufA)->bufB(h0)
    gather_agg<<<aggBlocks, 256, 0, stream>>>(x, rowptr, ep, bufA, N);
    sage_linear<128, true><<<linBlocks, 256, 0, stream>>>(x, bufA, W0, b0, bufB, N);

    // layer 1: agg(h0)->bufC ; linear(h0,bufC)->bufA(h1)
    gather_agg<<<aggBlocks, 256, 0, stream>>>(bufB, rowptr, ep, bufC, N);
    sage_linear<128, true><<<linBlocks, 256, 0, stream>>>(bufB, bufC, W1, b1, bufA, N);

    // layer 2: agg(h1)->bufB ; linear(h1,bufB)->out  (OUT=64, no relu)
    gather_agg<<<aggBlocks, 256, 0, stream>>>(bufA, rowptr, ep, bufB, N);
    sage_linear<64, false><<<linBlocks, 256, 0, stream>>>(bufA, bufB, W2, b2, out, N);
}